// Round 1
// baseline (1736.001 us; speedup 1.0000x reference)
//
#include <hip/hip_runtime.h>
#include <cstddef>

// Problem constants (hard-coded for this problem instance)
constexpr int B_  = 8;
constexpr int C_  = 512;
constexpr int KC_ = 256;
constexpr int M_  = 19;
constexpr int P_  = 128 * 128;  // 16384 pixels

// ---------------------------------------------------------------------------
// k/v projection: two-stage ConvBnRelu on proxy [B, C, M] -> [B, KC, M].
// One block per batch, 256 threads (thread == output channel).
// Everything staged through LDS; work is tiny (~20M MACs total).
// ---------------------------------------------------------------------------
__device__ __forceinline__ void two_stage_proj(
    const float* __restrict__ pS, float* __restrict__ t1,
    const float* __restrict__ W1, const float* __restrict__ s1, const float* __restrict__ b1,
    const float* __restrict__ W2, const float* __restrict__ s2, const float* __restrict__ b2,
    float* __restrict__ outg, int b, int tid)
{
    float acc[M_];
#pragma unroll
    for (int m = 0; m < M_; ++m) acc[m] = 0.f;

    // stage 1: o = tid, reduce over C_ (512). W row read as float4 (L2-resident).
    const float4* wrow = reinterpret_cast<const float4*>(W1 + (size_t)tid * C_);
    for (int c4 = 0; c4 < C_ / 4; ++c4) {
        float4 w = wrow[c4];
        const float* pr = pS + c4 * 4 * M_;
#pragma unroll
        for (int m = 0; m < M_; ++m) acc[m] = fmaf(w.x, pr[m], acc[m]);
#pragma unroll
        for (int m = 0; m < M_; ++m) acc[m] = fmaf(w.y, pr[M_ + m], acc[m]);
#pragma unroll
        for (int m = 0; m < M_; ++m) acc[m] = fmaf(w.z, pr[2 * M_ + m], acc[m]);
#pragma unroll
        for (int m = 0; m < M_; ++m) acc[m] = fmaf(w.w, pr[3 * M_ + m], acc[m]);
    }
    float s = s1[tid], bb = b1[tid];
    __syncthreads();  // protect t1 against readers from a previous use
#pragma unroll
    for (int m = 0; m < M_; ++m) t1[tid * M_ + m] = fmaxf(fmaf(acc[m], s, bb), 0.f);
    __syncthreads();

    // stage 2: reduce over KC_ (256) from LDS
#pragma unroll
    for (int m = 0; m < M_; ++m) acc[m] = 0.f;
    const float4* wrow2 = reinterpret_cast<const float4*>(W2 + (size_t)tid * KC_);
    for (int c4 = 0; c4 < KC_ / 4; ++c4) {
        float4 w = wrow2[c4];
        const float* tr = t1 + c4 * 4 * M_;
#pragma unroll
        for (int m = 0; m < M_; ++m) acc[m] = fmaf(w.x, tr[m], acc[m]);
#pragma unroll
        for (int m = 0; m < M_; ++m) acc[m] = fmaf(w.y, tr[M_ + m], acc[m]);
#pragma unroll
        for (int m = 0; m < M_; ++m) acc[m] = fmaf(w.z, tr[2 * M_ + m], acc[m]);
#pragma unroll
        for (int m = 0; m < M_; ++m) acc[m] = fmaf(w.w, tr[3 * M_ + m], acc[m]);
    }
    s = s2[tid]; bb = b2[tid];
#pragma unroll
    for (int m = 0; m < M_; ++m)
        outg[((size_t)b * KC_ + tid) * M_ + m] = fmaxf(fmaf(acc[m], s, bb), 0.f);
}

__global__ __launch_bounds__(256) void kv_kernel(
    const float* __restrict__ proxy,
    const float* __restrict__ Wo1, const float* __restrict__ so1, const float* __restrict__ bo1,
    const float* __restrict__ Wo2, const float* __restrict__ so2, const float* __restrict__ bo2,
    const float* __restrict__ Wd1, const float* __restrict__ sd1, const float* __restrict__ bd1,
    const float* __restrict__ Wd2, const float* __restrict__ sd2, const float* __restrict__ bd2,
    float* __restrict__ Kg, float* __restrict__ Vg)
{
    __shared__ float pS[C_ * M_];   // 38.9 KB
    __shared__ float t1[KC_ * M_];  // 19.5 KB
    const int b = blockIdx.x, tid = threadIdx.x;
    for (int i = tid; i < C_ * M_; i += 256) pS[i] = proxy[(size_t)b * C_ * M_ + i];
    __syncthreads();
    two_stage_proj(pS, t1, Wo1, so1, bo1, Wo2, so2, bo2, Kg, b, tid);
    __syncthreads();
    two_stage_proj(pS, t1, Wd1, sd1, bd1, Wd2, sd2, bd2, Vg, b, tid);
}

// ---------------------------------------------------------------------------
// fp32 CBR-GEMM:  Y[b,o,p] = relu(s[o] * sum_k W[o,k] * X[b,k,p] + bias[o])
// 64x64 output tile, BK=16, 256 threads, 4x4 microtile per thread.
// As padded to 65 to kill the transpose-store bank conflict.
// ---------------------------------------------------------------------------
template <int K>
__global__ __launch_bounds__(256) void cbr_gemm(
    const float* __restrict__ W,   // [O, K] row-major
    const float* __restrict__ X,   // [B, K, P]
    const float* __restrict__ sc, const float* __restrict__ bi,
    float* __restrict__ Y, int O)  // [B, O, P]
{
    __shared__ float As[16][65];   // As[k][m] = W[m0+m][k0+k]
    __shared__ float Bs[16][64];   // Bs[k][n] = X[k0+k][n0+n]

    const int tid = threadIdx.x;
    const int b  = blockIdx.z;
    const int n0 = blockIdx.x * 64;
    const int m0 = blockIdx.y * 64;
    const float* Xb = X + (size_t)b * K * P_;

    const int am = tid >> 2;          // 0..63  (A tile row)
    const int ak = (tid & 3) << 2;    // 0,4,8,12
    const int bk = tid >> 4;          // 0..15  (B tile row)
    const int bn = (tid & 15) << 2;   // 0..60
    const int ty = tid >> 4, tx = tid & 15;

    float acc[4][4] = {};

    for (int k0 = 0; k0 < K; k0 += 16) {
        float4 wa = *reinterpret_cast<const float4*>(W + (size_t)(m0 + am) * K + k0 + ak);
        float4 xb = *reinterpret_cast<const float4*>(Xb + (size_t)(k0 + bk) * P_ + n0 + bn);
        __syncthreads();  // previous iteration's readers done
        As[ak + 0][am] = wa.x;
        As[ak + 1][am] = wa.y;
        As[ak + 2][am] = wa.z;
        As[ak + 3][am] = wa.w;
        *reinterpret_cast<float4*>(&Bs[bk][bn]) = xb;
        __syncthreads();
#pragma unroll
        for (int kk = 0; kk < 16; ++kk) {
            float a[4], bv[4];
#pragma unroll
            for (int i = 0; i < 4; ++i) a[i] = As[kk][ty * 4 + i];
#pragma unroll
            for (int j = 0; j < 4; ++j) bv[j] = Bs[kk][tx * 4 + j];
#pragma unroll
            for (int i = 0; i < 4; ++i)
#pragma unroll
                for (int j = 0; j < 4; ++j)
                    acc[i][j] = fmaf(a[i], bv[j], acc[i][j]);
        }
    }

    float* Yb = Y + (size_t)b * O * P_;
#pragma unroll
    for (int i = 0; i < 4; ++i) {
        const int o = m0 + ty * 4 + i;
        const float s = sc[o], bb = bi[o];
        float4 r;
        r.x = fmaxf(fmaf(acc[i][0], s, bb), 0.f);
        r.y = fmaxf(fmaf(acc[i][1], s, bb), 0.f);
        r.z = fmaxf(fmaf(acc[i][2], s, bb), 0.f);
        r.w = fmaxf(fmaf(acc[i][3], s, bb), 0.f);
        *reinterpret_cast<float4*>(Yb + (size_t)o * P_ + n0 + tx * 4) = r;
    }
}

// ---------------------------------------------------------------------------
// Attention: thread == pixel. sim[p,m] = (1/16) q[:,p].k[:,m]; softmax over m;
// ctx[kc,p] = sum_m prob[m] v[kc,m]. ctx overwrites q IN PLACE (each (kc,p)
// element is read and written only by the unique thread owning pixel p).
// Memory-bound: 128 MB read + 128 MB write.
// ---------------------------------------------------------------------------
__global__ __launch_bounds__(256) void attn_kernel(
    float* __restrict__ Q,         // [B, KC, P] in, ctx out (in-place)
    const float* __restrict__ Kg,  // [B, KC, M]
    const float* __restrict__ Vg)  // [B, KC, M]
{
    __shared__ float kS[KC_ * M_];
    __shared__ float vS[KC_ * M_];
    const int b = blockIdx.y;
    const int p = blockIdx.x * 256 + threadIdx.x;
    for (int i = threadIdx.x; i < KC_ * M_; i += 256) {
        kS[i] = Kg[(size_t)b * KC_ * M_ + i];
        vS[i] = Vg[(size_t)b * KC_ * M_ + i];
    }
    __syncthreads();

    float sim[M_];
#pragma unroll
    for (int m = 0; m < M_; ++m) sim[m] = 0.f;

    float* Qb = Q + (size_t)b * KC_ * P_ + p;
    for (int kc = 0; kc < KC_; ++kc) {
        const float qv = Qb[(size_t)kc * P_];   // coalesced across threads
#pragma unroll
        for (int m = 0; m < M_; ++m) sim[m] = fmaf(qv, kS[kc * M_ + m], sim[m]);
    }

    // scale by KC^-0.5 = 1/16, softmax over m
    float mx = -1e30f;
#pragma unroll
    for (int m = 0; m < M_; ++m) { sim[m] *= 0.0625f; mx = fmaxf(mx, sim[m]); }
    float sum = 0.f;
#pragma unroll
    for (int m = 0; m < M_; ++m) { sim[m] = __expf(sim[m] - mx); sum += sim[m]; }
    const float inv = 1.f / sum;
#pragma unroll
    for (int m = 0; m < M_; ++m) sim[m] *= inv;

    for (int kc = 0; kc < KC_; ++kc) {
        float acc = 0.f;
#pragma unroll
        for (int m = 0; m < M_; ++m) acc = fmaf(sim[m], vS[kc * M_ + m], acc);
        Qb[(size_t)kc * P_] = acc;              // in-place, coalesced
    }
}

// ---------------------------------------------------------------------------
// Launch. Scratch plan:
//   d_out[0 .. 128MB)          : q1 (fully overwritten by final GEMM later)
//   d_out[128MB ..]            : k, v (311 KB; also overwritten at the end)
//   d_ws[0 .. 128MB)           : q2 / ctx (in-place attention)
// Final GEMM reads only q2 (ws) and writes all of d_out -> no aliasing hazard.
// ---------------------------------------------------------------------------
extern "C" void kernel_launch(void* const* d_in, const int* in_sizes, int n_in,
                              void* d_out, int out_size, void* d_ws, size_t ws_size,
                              hipStream_t stream)
{
    const float* x     = (const float*)d_in[0];
    const float* proxy = (const float*)d_in[1];
    const float* W_p1  = (const float*)d_in[2];
    const float* W_p2  = (const float*)d_in[3];
    const float* W_o1  = (const float*)d_in[4];
    const float* W_o2  = (const float*)d_in[5];
    const float* W_d1  = (const float*)d_in[6];
    const float* W_d2  = (const float*)d_in[7];
    const float* W_u   = (const float*)d_in[8];
    const float* s_p1  = (const float*)d_in[9];  const float* b_p1 = (const float*)d_in[10];
    const float* s_p2  = (const float*)d_in[11]; const float* b_p2 = (const float*)d_in[12];
    const float* s_o1  = (const float*)d_in[13]; const float* b_o1 = (const float*)d_in[14];
    const float* s_o2  = (const float*)d_in[15]; const float* b_o2 = (const float*)d_in[16];
    const float* s_d1  = (const float*)d_in[17]; const float* b_d1 = (const float*)d_in[18];
    const float* s_d2  = (const float*)d_in[19]; const float* b_d2 = (const float*)d_in[20];
    const float* s_u   = (const float*)d_in[21]; const float* b_u  = (const float*)d_in[22];

    float* out = (float*)d_out;
    float* q1  = out;                              // 128 MB scratch inside d_out
    float* Kg  = out + (size_t)B_ * KC_ * P_;      // d_out + 128 MB
    float* Vg  = Kg + (size_t)B_ * KC_ * M_;
    float* q2  = (float*)d_ws;                     // 128 MB in workspace

    // 1) k, v projections (tiny)
    kv_kernel<<<dim3(B_), dim3(256), 0, stream>>>(
        proxy, W_o1, s_o1, b_o1, W_o2, s_o2, b_o2,
               W_d1, s_d1, b_d1, W_d2, s_d2, b_d2, Kg, Vg);

    // 2) q1 = CBR(x, W_p1)            [B, KC, P], K = 512
    cbr_gemm<C_><<<dim3(P_ / 64, KC_ / 64, B_), dim3(256), 0, stream>>>(
        W_p1, x, s_p1, b_p1, q1, KC_);

    // 3) q2 = CBR(q1, W_p2)           [B, KC, P], K = 256
    cbr_gemm<KC_><<<dim3(P_ / 64, KC_ / 64, B_), dim3(256), 0, stream>>>(
        W_p2, q1, s_p2, b_p2, q2, KC_);

    // 4) attention: q2 -> ctx in place
    attn_kernel<<<dim3(P_ / 256, B_), dim3(256), 0, stream>>>(q2, Kg, Vg);

    // 5) out = CBR(ctx, W_u)          [B, C, P], K = 256
    cbr_gemm<KC_><<<dim3(P_ / 64, C_ / 64, B_), dim3(256), 0, stream>>>(
        W_u, q2, s_u, b_u, out, C_);
}

// Round 2
// 884.345 us; speedup vs baseline: 1.9630x; 1.9630x over previous
//
#include <hip/hip_runtime.h>
#include <hip/hip_bf16.h>
#include <cstddef>

// Problem constants
constexpr int B_  = 8;
constexpr int C_  = 512;
constexpr int KC_ = 256;
constexpr int M_  = 19;
constexpr int P_  = 128 * 128;  // 16384 pixels

typedef short frag8 __attribute__((ext_vector_type(8)));  // 8 bf16 (4 VGPRs)
typedef float f32x4 __attribute__((ext_vector_type(4)));  // 4 fp32 acc

__device__ __forceinline__ unsigned pk_bf16(float a, float b) {
    union { __hip_bfloat162 h; unsigned u; } cv;
    cv.h = __float22bfloat162_rn(make_float2(a, b));
    return cv.u;
}
__device__ __forceinline__ ushort bf16_1(float a) {
    union { __hip_bfloat16 h; ushort u; } cv;
    cv.h = __float2bfloat16(a);
    return cv.u;
}

// ---------------------------------------------------------------------------
// k/v projection (fp32, tiny): proxy [B,C,M] -> K,V [B,KC,M]
// ---------------------------------------------------------------------------
__device__ __forceinline__ void two_stage_proj(
    const float* __restrict__ pS, float* __restrict__ t1,
    const float* __restrict__ W1, const float* __restrict__ s1, const float* __restrict__ b1,
    const float* __restrict__ W2, const float* __restrict__ s2, const float* __restrict__ b2,
    float* __restrict__ outg, int b, int tid)
{
    float acc[M_];
#pragma unroll
    for (int m = 0; m < M_; ++m) acc[m] = 0.f;
    const float4* wrow = reinterpret_cast<const float4*>(W1 + (size_t)tid * C_);
    for (int c4 = 0; c4 < C_ / 4; ++c4) {
        float4 w = wrow[c4];
        const float* pr = pS + c4 * 4 * M_;
#pragma unroll
        for (int m = 0; m < M_; ++m) acc[m] = fmaf(w.x, pr[m], acc[m]);
#pragma unroll
        for (int m = 0; m < M_; ++m) acc[m] = fmaf(w.y, pr[M_ + m], acc[m]);
#pragma unroll
        for (int m = 0; m < M_; ++m) acc[m] = fmaf(w.z, pr[2 * M_ + m], acc[m]);
#pragma unroll
        for (int m = 0; m < M_; ++m) acc[m] = fmaf(w.w, pr[3 * M_ + m], acc[m]);
    }
    float s = s1[tid], bb = b1[tid];
    __syncthreads();
#pragma unroll
    for (int m = 0; m < M_; ++m) t1[tid * M_ + m] = fmaxf(fmaf(acc[m], s, bb), 0.f);
    __syncthreads();
#pragma unroll
    for (int m = 0; m < M_; ++m) acc[m] = 0.f;
    const float4* wrow2 = reinterpret_cast<const float4*>(W2 + (size_t)tid * KC_);
    for (int c4 = 0; c4 < KC_ / 4; ++c4) {
        float4 w = wrow2[c4];
        const float* tr = t1 + c4 * 4 * M_;
#pragma unroll
        for (int m = 0; m < M_; ++m) acc[m] = fmaf(w.x, tr[m], acc[m]);
#pragma unroll
        for (int m = 0; m < M_; ++m) acc[m] = fmaf(w.y, tr[M_ + m], acc[m]);
#pragma unroll
        for (int m = 0; m < M_; ++m) acc[m] = fmaf(w.z, tr[2 * M_ + m], acc[m]);
#pragma unroll
        for (int m = 0; m < M_; ++m) acc[m] = fmaf(w.w, tr[3 * M_ + m], acc[m]);
    }
    s = s2[tid]; bb = b2[tid];
#pragma unroll
    for (int m = 0; m < M_; ++m)
        outg[((size_t)b * KC_ + tid) * M_ + m] = fmaxf(fmaf(acc[m], s, bb), 0.f);
}

__global__ __launch_bounds__(256) void kv_kernel(
    const float* __restrict__ proxy,
    const float* __restrict__ Wo1, const float* __restrict__ so1, const float* __restrict__ bo1,
    const float* __restrict__ Wo2, const float* __restrict__ so2, const float* __restrict__ bo2,
    const float* __restrict__ Wd1, const float* __restrict__ sd1, const float* __restrict__ bd1,
    const float* __restrict__ Wd2, const float* __restrict__ sd2, const float* __restrict__ bd2,
    float* __restrict__ Kg, float* __restrict__ Vg)
{
    __shared__ float pS[C_ * M_];
    __shared__ float t1[KC_ * M_];
    const int b = blockIdx.x, tid = threadIdx.x;
    for (int i = tid; i < C_ * M_; i += 256) pS[i] = proxy[(size_t)b * C_ * M_ + i];
    __syncthreads();
    two_stage_proj(pS, t1, Wo1, so1, bo1, Wo2, so2, bo2, Kg, b, tid);
    __syncthreads();
    two_stage_proj(pS, t1, Wd1, sd1, bd1, Wd2, sd2, bd2, Vg, b, tid);
}

// ---------------------------------------------------------------------------
// bf16 MFMA CBR-GEMM:  Y[b,o,p] = relu(s[o]*sum_k W[o,k]*X[b,k,p] + bias[o])
// 128x128 block tile, BK=32, 4 waves each doing 64x64 via 4x4 16x16x32 MFMAs.
// A (weights, fp32 [O][K])  : cvt->bf16 in regs -> LDS As[m][k] (pitch 40)
// B (X, [K][P] fp32 or bf16): coalesced loads along p, reg-transpose ->
//                             LDS Bs[p][k] (pitch 40, k-contiguous for frags)
// Pitch 40 bf16 (80 B) => fragment reads alias 2-way max (free, m136).
// ---------------------------------------------------------------------------
template <int K, bool IN_F32, bool OUT_F32>
__global__ __launch_bounds__(256) void mfma_cbr(
    const float* __restrict__ W, const void* __restrict__ Xv,
    const float* __restrict__ sc, const float* __restrict__ bi,
    void* __restrict__ Yv, int O)
{
    __shared__ ushort As[128][40];
    __shared__ ushort Bs[128][40];

    const int tid = threadIdx.x;
    const int m0 = blockIdx.x * 128;          // m in grid.x: m-pairs adjacent -> L2 reuse of X tile
    const int n0 = blockIdx.y * 128;
    const int b  = blockIdx.z;
    const int wave = tid >> 6, lane = tid & 63;
    const int quad = lane >> 4, l15 = lane & 15;
    const int mq = (wave & 1) * 64, nq = (wave >> 1) * 64;

    // staging assignments
    const int am  = tid >> 1;                 // A row 0..127
    const int akh = (tid & 1) * 16;           // A k-half
    const int pp  = (tid & 63) * 2;           // B p-pair 0..126
    const int bkg = (tid >> 6) * 8;           // B k-group 0,8,16,24

    const float*  Wp = W + (size_t)(m0 + am) * K + akh;
    const float*  Xf = (const float*)Xv  + (size_t)b * K * P_ + n0 + pp;
    const ushort* Xh = (const ushort*)Xv + (size_t)b * K * P_ + n0 + pp;

    f32x4 acc[4][4];
#pragma unroll
    for (int i = 0; i < 4; ++i)
#pragma unroll
        for (int j = 0; j < 4; ++j) acc[i][j] = {0.f, 0.f, 0.f, 0.f};

    for (int k0 = 0; k0 < K; k0 += 32) {
        // ---- global loads (issue before barrier; overlap prev MFMAs) ----
        float4 wa0 = *(const float4*)(Wp + k0);
        float4 wa1 = *(const float4*)(Wp + k0 + 4);
        float4 wa2 = *(const float4*)(Wp + k0 + 8);
        float4 wa3 = *(const float4*)(Wp + k0 + 12);
        unsigned bd0[4], bd1[4];
        if constexpr (IN_F32) {
            float2 xr[8];
#pragma unroll
            for (int j = 0; j < 8; ++j)
                xr[j] = *(const float2*)(Xf + (size_t)(k0 + bkg + j) * P_);
#pragma unroll
            for (int i = 0; i < 4; ++i) {
                bd0[i] = pk_bf16(xr[2 * i].x, xr[2 * i + 1].x);   // row pp
                bd1[i] = pk_bf16(xr[2 * i].y, xr[2 * i + 1].y);   // row pp+1
            }
        } else {
            unsigned xr[8];
#pragma unroll
            for (int j = 0; j < 8; ++j)
                xr[j] = *(const unsigned*)(Xh + (size_t)(k0 + bkg + j) * P_);
#pragma unroll
            for (int i = 0; i < 4; ++i) {
                bd0[i] = (xr[2 * i] & 0xffffu) | (xr[2 * i + 1] << 16);
                bd1[i] = (xr[2 * i] >> 16)    | (xr[2 * i + 1] & 0xffff0000u);
            }
        }
        unsigned ad0[4] = { pk_bf16(wa0.x, wa0.y), pk_bf16(wa0.z, wa0.w),
                            pk_bf16(wa1.x, wa1.y), pk_bf16(wa1.z, wa1.w) };
        unsigned ad1[4] = { pk_bf16(wa2.x, wa2.y), pk_bf16(wa2.z, wa2.w),
                            pk_bf16(wa3.x, wa3.y), pk_bf16(wa3.z, wa3.w) };

        __syncthreads();   // prev tile's readers done
        *(int4*)(&As[am][akh])     = *(int4*)ad0;
        *(int4*)(&As[am][akh + 8]) = *(int4*)ad1;
        *(int4*)(&Bs[pp][bkg])     = *(int4*)bd0;
        *(int4*)(&Bs[pp + 1][bkg]) = *(int4*)bd1;
        __syncthreads();

        // ---- fragments + MFMA ----
        frag8 af[4], bfv[4];
#pragma unroll
        for (int f = 0; f < 4; ++f) {
            af[f]  = *(const frag8*)(&As[mq + f * 16 + l15][quad * 8]);
            bfv[f] = *(const frag8*)(&Bs[nq + f * 16 + l15][quad * 8]);
        }
#pragma unroll
        for (int i = 0; i < 4; ++i)
#pragma unroll
            for (int j = 0; j < 4; ++j)
                acc[i][j] = __builtin_amdgcn_mfma_f32_16x16x32_bf16(
                    af[i], bfv[j], acc[i][j], 0, 0, 0);
    }

    // ---- epilogue: scale+bias+relu, store ----
    // C/D layout: col = lane&15 (n), row = quad*4 + reg (m)  [m89-verified]
#pragma unroll
    for (int i = 0; i < 4; ++i) {
        const int ob = m0 + mq + i * 16 + quad * 4;
        float s[4], bbv[4];
#pragma unroll
        for (int r = 0; r < 4; ++r) { s[r] = sc[ob + r]; bbv[r] = bi[ob + r]; }
#pragma unroll
        for (int j = 0; j < 4; ++j) {
            const int p = n0 + nq + j * 16 + l15;
#pragma unroll
            for (int r = 0; r < 4; ++r) {
                float v = fmaxf(fmaf(acc[i][j][r], s[r], bbv[r]), 0.f);
                if constexpr (OUT_F32)
                    ((float*)Yv)[((size_t)b * O + ob + r) * P_ + p] = v;
                else
                    ((ushort*)Yv)[((size_t)b * O + ob + r) * P_ + p] = bf16_1(v);
            }
        }
    }
}

// ---------------------------------------------------------------------------
// Attention on bf16 q2 (in-place -> ctx). 2 pixels per thread (packed uint).
// K/V fp32 in LDS (broadcast). fp32 softmax.
// ---------------------------------------------------------------------------
__global__ __launch_bounds__(256) void attn_kernel(
    ushort* __restrict__ Q,        // [B, KC, P] bf16, in/out
    const float* __restrict__ Kg, const float* __restrict__ Vg)
{
    __shared__ float kS[KC_ * M_];
    __shared__ float vS[KC_ * M_];
    const int b = blockIdx.y;
    const int p = (blockIdx.x * 256 + threadIdx.x) * 2;
    for (int i = threadIdx.x; i < KC_ * M_; i += 256) {
        kS[i] = Kg[(size_t)b * KC_ * M_ + i];
        vS[i] = Vg[(size_t)b * KC_ * M_ + i];
    }
    __syncthreads();

    float s0[M_], s1[M_];
#pragma unroll
    for (int m = 0; m < M_; ++m) { s0[m] = 0.f; s1[m] = 0.f; }

    unsigned* Qb = reinterpret_cast<unsigned*>(Q + (size_t)b * KC_ * P_ + p);
    for (int kc = 0; kc < KC_; ++kc) {
        unsigned u = Qb[(size_t)kc * (P_ / 2)];
        float qa = __uint_as_float(u << 16);
        float qb = __uint_as_float(u & 0xffff0000u);
        const float* kr = kS + kc * M_;
#pragma unroll
        for (int m = 0; m < M_; ++m) {
            s0[m] = fmaf(qa, kr[m], s0[m]);
            s1[m] = fmaf(qb, kr[m], s1[m]);
        }
    }

    float mx0 = -1e30f, mx1 = -1e30f;
#pragma unroll
    for (int m = 0; m < M_; ++m) {
        s0[m] *= 0.0625f; s1[m] *= 0.0625f;
        mx0 = fmaxf(mx0, s0[m]); mx1 = fmaxf(mx1, s1[m]);
    }
    float sum0 = 0.f, sum1 = 0.f;
#pragma unroll
    for (int m = 0; m < M_; ++m) {
        s0[m] = __expf(s0[m] - mx0); sum0 += s0[m];
        s1[m] = __expf(s1[m] - mx1); sum1 += s1[m];
    }
    const float i0 = 1.f / sum0, i1 = 1.f / sum1;
#pragma unroll
    for (int m = 0; m < M_; ++m) { s0[m] *= i0; s1[m] *= i1; }

    for (int kc = 0; kc < KC_; ++kc) {
        const float* vr = vS + kc * M_;
        float a0 = 0.f, a1 = 0.f;
#pragma unroll
        for (int m = 0; m < M_; ++m) {
            a0 = fmaf(s0[m], vr[m], a0);
            a1 = fmaf(s1[m], vr[m], a1);
        }
        Qb[(size_t)kc * (P_ / 2)] = pk_bf16(a0, a1);
    }
}

// ---------------------------------------------------------------------------
// Launch. Scratch:
//   d_ws[0 .. 64MB)   : q1 bf16 [B,KC,P]
//   d_ws[64 .. 128MB) : q2/ctx bf16 [B,KC,P] (in-place attention)
//   d_out[0 ..)       : K,V fp32 (dead before final GEMM overwrites d_out)
// ---------------------------------------------------------------------------
extern "C" void kernel_launch(void* const* d_in, const int* in_sizes, int n_in,
                              void* d_out, int out_size, void* d_ws, size_t ws_size,
                              hipStream_t stream)
{
    const float* x     = (const float*)d_in[0];
    const float* proxy = (const float*)d_in[1];
    const float* W_p1  = (const float*)d_in[2];
    const float* W_p2  = (const float*)d_in[3];
    const float* W_o1  = (const float*)d_in[4];
    const float* W_o2  = (const float*)d_in[5];
    const float* W_d1  = (const float*)d_in[6];
    const float* W_d2  = (const float*)d_in[7];
    const float* W_u   = (const float*)d_in[8];
    const float* s_p1  = (const float*)d_in[9];  const float* b_p1 = (const float*)d_in[10];
    const float* s_p2  = (const float*)d_in[11]; const float* b_p2 = (const float*)d_in[12];
    const float* s_o1  = (const float*)d_in[13]; const float* b_o1 = (const float*)d_in[14];
    const float* s_o2  = (const float*)d_in[15]; const float* b_o2 = (const float*)d_in[16];
    const float* s_d1  = (const float*)d_in[17]; const float* b_d1 = (const float*)d_in[18];
    const float* s_d2  = (const float*)d_in[19]; const float* b_d2 = (const float*)d_in[20];
    const float* s_u   = (const float*)d_in[21]; const float* b_u  = (const float*)d_in[22];

    float* out = (float*)d_out;
    float* Kg  = out;                         // scratch in d_out (dead before final GEMM)
    float* Vg  = Kg + (size_t)B_ * KC_ * M_;
    ushort* q1 = (ushort*)d_ws;
    ushort* q2 = q1 + (size_t)B_ * KC_ * P_;  // +64 MB

    // 1) k, v projections (tiny, fp32)
    kv_kernel<<<dim3(B_), dim3(256), 0, stream>>>(
        proxy, W_o1, s_o1, b_o1, W_o2, s_o2, b_o2,
               W_d1, s_d1, b_d1, W_d2, s_d2, b_d2, Kg, Vg);

    // 2) q1 = CBR(x, W_p1)   fp32 in, bf16 out, K=512
    mfma_cbr<C_, true, false><<<dim3(KC_ / 128, P_ / 128, B_), dim3(256), 0, stream>>>(
        W_p1, x, s_p1, b_p1, q1, KC_);

    // 3) q2 = CBR(q1, W_p2)  bf16 in, bf16 out, K=256
    mfma_cbr<KC_, false, false><<<dim3(KC_ / 128, P_ / 128, B_), dim3(256), 0, stream>>>(
        W_p2, q1, s_p2, b_p2, q2, KC_);

    // 4) attention: q2 -> ctx in place (bf16)
    attn_kernel<<<dim3(P_ / 512, B_), dim3(256), 0, stream>>>(q2, Kg, Vg);

    // 5) out = CBR(ctx, W_u) bf16 in, fp32 out, K=256
    mfma_cbr<KC_, false, true><<<dim3(C_ / 128, P_ / 128, B_), dim3(256), 0, stream>>>(
        W_u, q2, s_u, b_u, out, C_);
}